// Round 7
// baseline (51.920 us; speedup 1.0000x reference)
//
#include <hip/hip_runtime.h>

constexpr int H = 192, W = 192, D = 192;
constexpr int BH = 8, BW = 8, BZ = 16;     // output tile per block
constexpr int TY = 16, TX = 16, TZ = 24;   // staged: halo -4..+11 (x,y), -4..+19 (z)
constexpr int TILE_N = TY * TX * TZ;       // 6144 dwords = 24 KB -> 6 blocks/CU
constexpr int NCHUNK = TILE_N / 4;         // 1536 16B chunks
constexpr int NINSTR = NCHUNK / 64;        // 24 wave-instructions

// Exact reference semantics for one voxel, all-global (fallback path).
__device__ __forceinline__ float ref_voxel(const float* __restrict__ I,
                                           float x, float y, float zf)
{
    int fx = (int)floorf(x), fy = (int)floorf(y), fz = (int)floorf(zf);
    int x0 = min(max(fx, 0), W + 1), x1 = min(max(fx + 1, 0), W + 1);
    int y0 = min(max(fy, 0), H + 1), y1 = min(max(fy + 1, 0), H + 1);
    int zp0 = min(max(fz, 0), D + 1), zp1 = min(max(fz + 1, 0), D + 1);
    float dx = (float)x1 - x, dy = (float)y1 - y, dz = (float)zp1 - zf;
    int xi0 = x0 - 1, xi1 = x1 - 1, yi0 = y0 - 1, yi1 = y1 - 1;
    int zi = zp0 - 1, zj = zp1 - 1;
    float ax0 = ((unsigned)xi0 < (unsigned)W) ? dx       : 0.f;
    float ax1 = ((unsigned)xi1 < (unsigned)W) ? 1.f - dx : 0.f;
    float ay0 = ((unsigned)yi0 < (unsigned)H) ? dy       : 0.f;
    float ay1 = ((unsigned)yi1 < (unsigned)H) ? 1.f - dy : 0.f;
    float az0 = ((unsigned)zi  < (unsigned)D) ? dz       : 0.f;
    float az1 = ((unsigned)zj  < (unsigned)D) ? 1.f - dz : 0.f;
    int xc0 = min(max(xi0, 0), W - 1), xc1 = min(max(xi1, 0), W - 1);
    int yc0 = min(max(yi0, 0), H - 1), yc1 = min(max(yi1, 0), H - 1);
    int zc0 = min(max(zi, 0), D - 1),  zc1 = min(max(zj, 0), D - 1);
    const float* r00 = I + (yc0 * W + xc0) * D;
    const float* r01 = I + (yc0 * W + xc1) * D;
    const float* r10 = I + (yc1 * W + xc0) * D;
    const float* r11 = I + (yc1 * W + xc1) * D;
    float s00 = az0 * r00[zc0] + az1 * r00[zc1];
    float s01 = az0 * r01[zc0] + az1 * r01[zc1];
    float s10 = az0 * r10[zc0] + az1 * r10[zc1];
    float s11 = az0 * r11[zc0] + az1 * r11[zc1];
    return ay0 * (ax0 * s00 + ax1 * s01) + ay1 * (ax0 * s10 + ax1 * s11);
}

__global__ __launch_bounds__(256, 8) void st_tile(
    const float* __restrict__ I,
    const float* __restrict__ dxt,
    const float* __restrict__ dyt,
    const float* __restrict__ dzt,
    float* __restrict__ out)
{
    __shared__ float tile[TILE_N];   // 24 KB -> 6 blocks/CU, 24 waves/CU

    const int tid = threadIdx.x;
    const int bx = blockIdx.x, by = blockIdx.y, bz = blockIdx.z;
    const int w0 = bx * BW, h0 = by * BH, z0 = bz * BZ;
    const int xg0 = w0 - 4, yg0 = h0 - 4, zg0 = z0 - 4;

    // ---- staging: global_load_lds, per-lane CLAMPED source, linear LDS dest ----
    // chunk c holds tile dwords [4c,4c+3]: row c/6 (=ry*16+rx), z-seg (c%6)*4.
    // Clamped-duplicate slots are never addressed by compute (lz/lx/ly of any
    // in-volume clamped coord always lands in the true-data region) [R6-verified].
    {
        const unsigned wv = tid >> 6, lane = tid & 63;
        #pragma unroll
        for (unsigned t = 0; t < (unsigned)(NINSTR / 4); ++t) {
            unsigned i = wv + t * 4u;
            unsigned c = i * 64u + lane;
            unsigned row = c / 6u;
            unsigned s = c - row * 6u;
            unsigned ry = row >> 4, rx = row & 15u;
            int gy = min(max(yg0 + (int)ry, 0), H - 1);
            int gx = min(max(xg0 + (int)rx, 0), W - 1);
            int zs = min(max(zg0 + (int)(s * 4u), 0), D - 4);
            const float* src = I + ((gy * W + gx) * D + zs);
            __builtin_amdgcn_global_load_lds(
                (const __attribute__((address_space(1))) void*)src,
                (__attribute__((address_space(3))) void*)(tile + i * 256u),
                16, 0, 0);
        }
    }

    // displacement loads (in flight alongside staging; drained together)
    const int zq = tid & 3, wl = (tid >> 2) & 7, hl = tid >> 5;
    const int wg = w0 + wl, hg = h0 + hl;
    const int t4 = (hg * W + wg) * (D / 4) + (z0 >> 2) + zq;
    float4 vx = reinterpret_cast<const float4*>(dxt)[t4];
    float4 vy = reinterpret_cast<const float4*>(dyt)[t4];
    float4 vz = reinterpret_cast<const float4*>(dzt)[t4];

    asm volatile("s_waitcnt vmcnt(0)" ::: "memory");
    __syncthreads();

    float rxj[4] = {vx.x, vx.y, vx.z, vx.w};
    float ryj[4] = {vy.x, vy.y, vy.z, vy.w};
    float rzj[4] = {vz.x, vz.y, vz.z, vz.w};
    float ro[4];

    // ---- unified compute: full reference clamp semantics (R6-verified) ----
    #pragma unroll
    for (int j = 0; j < 4; ++j) {
        const int zv = z0 + zq * 4 + j;
        float x  = rxj[j] + (float)(wg + 1);
        float y  = ryj[j] + (float)(hg + 1);
        float zf = rzj[j] + (float)(zv + 1);

        int fx = (int)floorf(x), fy = (int)floorf(y), fz = (int)floorf(zf);
        int x0 = min(max(fx, 0), W + 1), x1 = min(max(fx + 1, 0), W + 1);
        int y0 = min(max(fy, 0), H + 1), y1 = min(max(fy + 1, 0), H + 1);
        int zp0 = min(max(fz, 0), D + 1), zp1 = min(max(fz + 1, 0), D + 1);

        float dx = (float)x1 - x, dy = (float)y1 - y, dz = (float)zp1 - zf;

        int xi0 = x0 - 1, xi1 = x1 - 1, yi0 = y0 - 1, yi1 = y1 - 1;
        int zi = zp0 - 1, zj2 = zp1 - 1;

        float ax0 = ((unsigned)xi0 < (unsigned)W) ? dx       : 0.f;
        float ax1 = ((unsigned)xi1 < (unsigned)W) ? 1.f - dx : 0.f;
        float ay0 = ((unsigned)yi0 < (unsigned)H) ? dy       : 0.f;
        float ay1 = ((unsigned)yi1 < (unsigned)H) ? 1.f - dy : 0.f;
        float az0 = ((unsigned)zi  < (unsigned)D) ? dz       : 0.f;
        float az1 = ((unsigned)zj2 < (unsigned)D) ? 1.f - dz : 0.f;

        int xc0 = min(max(xi0, 0), W - 1), xc1 = min(max(xi1, 0), W - 1);
        int yc0 = min(max(yi0, 0), H - 1), yc1 = min(max(yi1, 0), H - 1);
        int zc  = min(max(zi, 0), D - 2);

        bool zlo = (zi <= D - 2);
        bool zhi = (zi >= 0);

        int lx0 = xc0 - xg0, lx1 = xc1 - xg0;
        int ly0 = yc0 - yg0, ly1 = yc1 - yg0;
        int lz  = zc - zg0;

        bool ok = ((unsigned)lx0 <= (unsigned)(TX - 1))
                & ((unsigned)lx1 <= (unsigned)(TX - 1))
                & ((unsigned)ly0 <= (unsigned)(TY - 1))
                & ((unsigned)ly1 <= (unsigned)(TY - 1))
                & ((unsigned)lz  <= (unsigned)(TZ - 2));

        // clamp bases so LDS loads are always legal; bad lanes overwritten below
        int b00 = min(max((ly0 * TX + lx0) * TZ + lz, 0), TILE_N - 2);
        int b01 = min(max((ly0 * TX + lx1) * TZ + lz, 0), TILE_N - 2);
        int b10 = min(max((ly1 * TX + lx0) * TZ + lz, 0), TILE_N - 2);
        int b11 = min(max((ly1 * TX + lx1) * TZ + lz, 0), TILE_N - 2);

        float a0 = tile[b00], a1 = tile[b00 + 1];
        float b0 = tile[b01], b1 = tile[b01 + 1];
        float c0 = tile[b10], c1 = tile[b10 + 1];
        float d0 = tile[b11], d1 = tile[b11 + 1];

        float v000 = zlo ? a0 : a1, v001 = zhi ? a1 : a0;
        float v010 = zlo ? b0 : b1, v011 = zhi ? b1 : b0;
        float v100 = zlo ? c0 : c1, v101 = zhi ? c1 : c0;
        float v110 = zlo ? d0 : d1, v111 = zhi ? d1 : d0;
        float s00 = az0 * v000 + az1 * v001;
        float s01 = az0 * v010 + az1 * v011;
        float s10 = az0 * v100 + az1 * v101;
        float s11 = az0 * v110 + az1 * v111;
        float r = ay0 * (ax0 * s00 + ax1 * s01)
                + ay1 * (ax0 * s10 + ax1 * s11);

        ro[j] = __builtin_expect(ok, 1) ? r : ref_voxel(I, x, y, zf);
    }

    reinterpret_cast<float4*>(out)[t4] = make_float4(ro[0], ro[1], ro[2], ro[3]);
}

extern "C" void kernel_launch(void* const* d_in, const int* in_sizes, int n_in,
                              void* d_out, int out_size, void* d_ws, size_t ws_size,
                              hipStream_t stream) {
    const float* I   = (const float*)d_in[0];
    const float* dxt = (const float*)d_in[1];
    const float* dyt = (const float*)d_in[2];
    const float* dzt = (const float*)d_in[3];
    float* out = (float*)d_out;

    dim3 grid(W / BW, H / BH, D / BZ);   // 24 x 24 x 12
    hipLaunchKernelGGL(st_tile, grid, dim3(256), 0, stream,
                       I, dxt, dyt, dzt, out);
}